// Round 3
// baseline (370.212 us; speedup 1.0000x reference)
//
#include <hip/hip_runtime.h>
#include <math.h>

// EdgeFeaturizer: per-row top-12 smallest of 8192x8192 fp32 + 50-bin RBF.
// d_out (float32): [8192*12*2] edge_index encoded as floats, then
// [8192*12*50] features.
//
// Wave-per-row; candidates d < CAND_T compacted via ballot+popc prefix;
// O(count^2) rank-select on ~82 keys. Key = (float_bits<<32)|idx ==
// top_k's (dist asc, idx asc) order. Exact fallback for any input.
//
// R3 change: per-row ROTATED chunk order for the scan. All 8192 rows are
// resident simultaneously; un-rotated, every wave reads the same within-row
// offset at the same time -> pure 32KiB power-of-2 stride across the device,
// which serializes on the HBM channel hash. Rotating the 1KiB-chunk start by
// (row & 31) spreads concurrent accesses over all within-row offsets.

#define N_ATOMS 8192
#define K 12
#define NBINS 50
#define CAP 256          // candidates/row ~ Binom(8192,0.01): mean 82, max ~120
#define WAVES 4
#define BLOCK (WAVES * 64)
#define MAX_RADIUS 8.0f
#define CAND_T 0.01f
#define CHUNKS 32        // N_ATOMS / (64 lanes * 4 floats)

__global__ __launch_bounds__(BLOCK) void edge_kernel(const float* __restrict__ dm,
                                                     float* __restrict__ out) {
    const int wave = threadIdx.x >> 6;
    const int lane = threadIdx.x & 63;
    const int row = blockIdx.x * WAVES + wave;
    const float* rowp = dm + (size_t)row * N_ATOMS;
    const float4* row4 = (const float4*)rowp;

    __shared__ unsigned long long s_keys[WAVES][CAP];
    __shared__ int s_selidx[WAVES][K];
    __shared__ float s_seldist[WAVES][K];

    const unsigned long long lane_below = (1ull << lane) - 1ull;
    const int rot = row & (CHUNKS - 1);

    // ---- scan: coalesced float4, rotated chunk order, ballot-compact ----
    int count = 0;
    #pragma unroll 4
    for (int i = 0; i < CHUNKS; ++i) {
        int chunk = (i + rot) & (CHUNKS - 1);
        int v4 = lane + chunk * 64;
        float4 v = row4[v4];
        int bidx = v4 * 4;
        float vals[4] = {v.x, v.y, v.z, v.w};
        #pragma unroll
        for (int c = 0; c < 4; ++c) {
            float d = vals[c];
            bool pred = d < CAND_T;
            unsigned long long m = __ballot(pred);
            if (pred) {
                int pos = count + __popcll(m & lane_below);
                if (pos < CAP)
                    s_keys[wave][pos] =
                        ((unsigned long long)__float_as_uint(d) << 32) |
                        (unsigned int)(bidx + c);
            }
            count += __popcll(m);
        }
    }
    __syncthreads();  // LDS write->read visibility

    if (count >= K && count <= CAP) {
        // ---- rank select: rank = #keys strictly smaller (keys unique) ----
        // Array order is rotation-scrambled but ranking is order-invariant.
        for (int j = lane; j < count; j += 64) {
            unsigned long long kj = s_keys[wave][j];
            int rank = 0;
            for (int m2 = 0; m2 < count; ++m2)       // broadcast reads
                rank += (s_keys[wave][m2] < kj) ? 1 : 0;
            if (rank < K) {
                s_selidx[wave][rank] = (int)(kj & 0xFFFFFFFFull);
                s_seldist[wave][rank] =
                    __uint_as_float((unsigned int)(kj >> 32));
            }
        }
    } else {
        // ---- exact per-wave fallback (never taken on this input) ----
        unsigned long long last = 0ull;
        for (int r = 0; r < K; ++r) {
            unsigned long long best = ~0ull;
            for (int i = 0; i < CHUNKS; ++i) {
                int v4 = lane + i * 64;
                float4 v = row4[v4];
                int bidx = v4 * 4;
                float vals[4] = {v.x, v.y, v.z, v.w};
                #pragma unroll
                for (int c = 0; c < 4; ++c) {
                    float d = vals[c];
                    float md = (d <= MAX_RADIUS) ? d
                                                 : __uint_as_float(0x7F800000u);
                    unsigned long long key =
                        ((unsigned long long)__float_as_uint(md) << 32) |
                        (unsigned int)(bidx + c);
                    if (((r == 0) || (key > last)) && key < best) best = key;
                }
            }
            #pragma unroll
            for (int off = 32; off > 0; off >>= 1) {
                unsigned long long other = __shfl_xor(best, off, 64);
                if (other < best) best = other;
            }
            if (lane == 0) {
                int idx = (int)(best & 0xFFFFFFFFull);
                s_selidx[wave][r] = idx;
                s_seldist[wave][r] = rowp[idx];  // original dm value
            }
            last = best;
        }
    }

    // ---- outputs ----
    float* out_ei = out;
    float* out_ef = out + (size_t)N_ATOMS * K * 2;
    if (lane < 2 * K) {
        int r = lane >> 1, comp = lane & 1;
        out_ei[((size_t)row * K + r) * 2 + comp] =
            comp ? (float)s_selidx[wave][r] : (float)row;
    }
    for (int t = lane; t < K * NBINS; t += 64) {
        int r = t / NBINS, b = t - r * NBINS;
        float d = s_seldist[wave][r];
        float z = (d - (float)b * (1.0f / 49.0f)) * 5.0f;
        out_ef[(size_t)row * K * NBINS + t] = __expf(-0.5f * z * z);
    }
}

extern "C" void kernel_launch(void* const* d_in, const int* in_sizes, int n_in,
                              void* d_out, int out_size, void* d_ws, size_t ws_size,
                              hipStream_t stream) {
    const float* dm = (const float*)d_in[0];
    float* out = (float*)d_out;
    edge_kernel<<<N_ATOMS / WAVES, BLOCK, 0, stream>>>(dm, out);
}

// Round 4
// 362.252 us; speedup vs baseline: 1.0220x; 1.0220x over previous
//
#include <hip/hip_runtime.h>
#include <math.h>

// EdgeFeaturizer: per-row top-12 smallest of 8192x8192 fp32 + 50-bin RBF.
// d_out (float32): [8192*12*2] edge_index encoded as floats, then
// [8192*12*50] features.
//
// R4: decouple streaming from candidate handling. Hot loop is pure
// load + compare + (rare) predicated per-lane LDS append — no ballots, no
// cross-lane deps, loads batched 8-deep for MLP. Compaction (shfl prefix
// sum) runs once per row after the stream. Rank-select on compacted keys;
// key=(float_bits<<32)|idx == top_k's (dist asc, idx asc) order.
// Exact per-wave fallback guarantees correctness for any input.

#define N_ATOMS 8192
#define K 12
#define NBINS 50
#define CAP 192          // total candidates/row: Binom(8192,0.01) mean 82
#define CAP_LANE 12      // per-lane: Poisson(1.28), P(>12) ~ 1e-9
#define WAVES 4
#define BLOCK (WAVES * 64)
#define MAX_RADIUS 8.0f
#define CAND_T 0.01f

__global__ __launch_bounds__(BLOCK) void edge_kernel(const float* __restrict__ dm,
                                                     float* __restrict__ out) {
    const int wave = threadIdx.x >> 6;
    const int lane = threadIdx.x & 63;
    const int row = blockIdx.x * WAVES + wave;
    const float* rowp = dm + (size_t)row * N_ATOMS;
    const float4* row4 = (const float4*)rowp;

    __shared__ unsigned long long s_lane[WAVES][64][CAP_LANE];  // 24 KiB
    __shared__ unsigned long long s_keys[WAVES][CAP];           // 6 KiB
    __shared__ int s_selidx[WAVES][K];
    __shared__ float s_seldist[WAVES][K];

    // ---- phase 1: pure streaming scan, per-lane private append ----
    int cnt = 0;  // raw candidate count for this lane (may exceed CAP_LANE)
    #pragma unroll
    for (int i = 0; i < 4; ++i) {
        float4 v[8];
        #pragma unroll
        for (int j = 0; j < 8; ++j)
            v[j] = row4[lane + (i * 8 + j) * 64];   // 8 loads in flight
        #pragma unroll
        for (int j = 0; j < 8; ++j) {
            int bidx = (lane + (i * 8 + j) * 64) * 4;
            float vals[4] = {v[j].x, v[j].y, v[j].z, v[j].w};
            #pragma unroll
            for (int c = 0; c < 4; ++c) {
                float d = vals[c];
                if (d < CAND_T) {
                    if (cnt < CAP_LANE)
                        s_lane[wave][lane][cnt] =
                            ((unsigned long long)__float_as_uint(d) << 32) |
                            (unsigned int)(bidx + c);
                    cnt++;
                }
            }
        }
    }

    // ---- phase 2: compaction via shfl prefix sum ----
    bool lane_ovf = cnt > CAP_LANE;
    int stored = lane_ovf ? CAP_LANE : cnt;
    int incl = stored;
    #pragma unroll
    for (int off = 1; off < 64; off <<= 1) {
        int o = __shfl_up(incl, off, 64);
        if (lane >= off) incl += o;
    }
    int excl = incl - stored;
    int total = __shfl(incl, 63, 64);
    bool ovf = __ballot(lane_ovf) != 0ull;

    if (!ovf && total <= CAP) {
        for (int t = 0; t < stored; ++t)
            s_keys[wave][excl + t] = s_lane[wave][lane][t];
    }
    __syncthreads();  // LDS write->read visibility

    if (!ovf && total >= K && total <= CAP) {
        // ---- rank select: rank = #keys strictly smaller (keys unique) ----
        for (int j = lane; j < total; j += 64) {
            unsigned long long kj = s_keys[wave][j];
            int rank = 0;
            for (int m2 = 0; m2 < total; ++m2)       // broadcast reads
                rank += (s_keys[wave][m2] < kj) ? 1 : 0;
            if (rank < K) {
                s_selidx[wave][rank] = (int)(kj & 0xFFFFFFFFull);
                s_seldist[wave][rank] =
                    __uint_as_float((unsigned int)(kj >> 32));
            }
        }
    } else {
        // ---- exact per-wave fallback (never taken on this input) ----
        unsigned long long last = 0ull;
        for (int r = 0; r < K; ++r) {
            unsigned long long best = ~0ull;
            for (int i = 0; i < 32; ++i) {
                int v4 = lane + i * 64;
                float4 v = row4[v4];
                int bidx = v4 * 4;
                float vals[4] = {v.x, v.y, v.z, v.w};
                #pragma unroll
                for (int c = 0; c < 4; ++c) {
                    float d = vals[c];
                    float md = (d <= MAX_RADIUS) ? d
                                                 : __uint_as_float(0x7F800000u);
                    unsigned long long key =
                        ((unsigned long long)__float_as_uint(md) << 32) |
                        (unsigned int)(bidx + c);
                    if (((r == 0) || (key > last)) && key < best) best = key;
                }
            }
            #pragma unroll
            for (int off = 32; off > 0; off >>= 1) {
                unsigned long long other = __shfl_xor(best, off, 64);
                if (other < best) best = other;
            }
            if (lane == 0) {
                int idx = (int)(best & 0xFFFFFFFFull);
                s_selidx[wave][r] = idx;
                s_seldist[wave][r] = rowp[idx];  // original dm value
            }
            last = best;
        }
    }

    // ---- outputs ----
    float* out_ei = out;
    float* out_ef = out + (size_t)N_ATOMS * K * 2;
    if (lane < 2 * K) {
        int r = lane >> 1, comp = lane & 1;
        out_ei[((size_t)row * K + r) * 2 + comp] =
            comp ? (float)s_selidx[wave][r] : (float)row;
    }
    for (int t = lane; t < K * NBINS; t += 64) {
        int r = t / NBINS, b = t - r * NBINS;
        float d = s_seldist[wave][r];
        float z = (d - (float)b * (1.0f / 49.0f)) * 5.0f;
        out_ef[(size_t)row * K * NBINS + t] = __expf(-0.5f * z * z);
    }
}

extern "C" void kernel_launch(void* const* d_in, const int* in_sizes, int n_in,
                              void* d_out, int out_size, void* d_ws, size_t ws_size,
                              hipStream_t stream) {
    const float* dm = (const float*)d_in[0];
    float* out = (float*)d_out;
    edge_kernel<<<N_ATOMS / WAVES, BLOCK, 0, stream>>>(dm, out);
}

// Round 5
// 343.558 us; speedup vs baseline: 1.0776x; 1.0544x over previous
//
#include <hip/hip_runtime.h>
#include <math.h>

// EdgeFeaturizer: per-row top-12 smallest of 8192x8192 fp32 + 50-bin RBF.
// d_out (float32): [8192*12*2] edge_index encoded as floats, then
// [8192*12*50] features.
//
// R5: NON-TEMPORAL streaming loads. The harness re-poisons d_ws (1 GiB) to
// 0xAA before every timed replay; those writes sit dirty in the 256 MiB
// Infinity Cache. A normal (allocating) 256 MiB read stream forces ~256 MiB
// of dirty writebacks concurrently with the reads (~2x kernel time). nt
// loads don't allocate -> no forced evictions. Scan structure (per-lane
// buckets + shfl-prefix compaction + rank select) carried from R4.
// Key=(float_bits<<32)|idx == top_k's (dist asc, idx asc) order.
// Exact per-wave fallback guarantees correctness for any input.

#define N_ATOMS 8192
#define K 12
#define NBINS 50
#define CAP 192          // total candidates/row: Binom(8192,0.01) mean 82
#define CAP_LANE 12      // per-lane: Poisson(1.28), P(>12) ~ 1e-9
#define WAVES 4
#define BLOCK (WAVES * 64)
#define MAX_RADIUS 8.0f
#define CAND_T 0.01f

typedef float f4 __attribute__((ext_vector_type(4)));

__global__ __launch_bounds__(BLOCK) void edge_kernel(const float* __restrict__ dm,
                                                     float* __restrict__ out) {
    const int wave = threadIdx.x >> 6;
    const int lane = threadIdx.x & 63;
    const int row = blockIdx.x * WAVES + wave;
    const float* rowp = dm + (size_t)row * N_ATOMS;
    const f4* row4 = (const f4*)rowp;

    __shared__ unsigned long long s_lane[WAVES][64][CAP_LANE];  // 24 KiB
    __shared__ unsigned long long s_keys[WAVES][CAP];           // 6 KiB
    __shared__ int s_selidx[WAVES][K];
    __shared__ float s_seldist[WAVES][K];

    // ---- phase 1: non-temporal streaming scan, per-lane private append ----
    int cnt = 0;  // raw candidate count for this lane (may exceed CAP_LANE)
    #pragma unroll
    for (int i = 0; i < 4; ++i) {
        f4 v[8];
        #pragma unroll
        for (int j = 0; j < 8; ++j)
            v[j] = __builtin_nontemporal_load(&row4[lane + (i * 8 + j) * 64]);
        #pragma unroll
        for (int j = 0; j < 8; ++j) {
            int bidx = (lane + (i * 8 + j) * 64) * 4;
            #pragma unroll
            for (int c = 0; c < 4; ++c) {
                float d = v[j][c];
                if (d < CAND_T) {
                    if (cnt < CAP_LANE)
                        s_lane[wave][lane][cnt] =
                            ((unsigned long long)__float_as_uint(d) << 32) |
                            (unsigned int)(bidx + c);
                    cnt++;
                }
            }
        }
    }

    // ---- phase 2: compaction via shfl prefix sum ----
    bool lane_ovf = cnt > CAP_LANE;
    int stored = lane_ovf ? CAP_LANE : cnt;
    int incl = stored;
    #pragma unroll
    for (int off = 1; off < 64; off <<= 1) {
        int o = __shfl_up(incl, off, 64);
        if (lane >= off) incl += o;
    }
    int excl = incl - stored;
    int total = __shfl(incl, 63, 64);
    bool ovf = __ballot(lane_ovf) != 0ull;

    if (!ovf && total <= CAP) {
        for (int t = 0; t < stored; ++t)
            s_keys[wave][excl + t] = s_lane[wave][lane][t];
    }
    __syncthreads();  // LDS write->read visibility

    if (!ovf && total >= K && total <= CAP) {
        // ---- rank select: rank = #keys strictly smaller (keys unique) ----
        for (int j = lane; j < total; j += 64) {
            unsigned long long kj = s_keys[wave][j];
            int rank = 0;
            for (int m2 = 0; m2 < total; ++m2)       // broadcast reads
                rank += (s_keys[wave][m2] < kj) ? 1 : 0;
            if (rank < K) {
                s_selidx[wave][rank] = (int)(kj & 0xFFFFFFFFull);
                s_seldist[wave][rank] =
                    __uint_as_float((unsigned int)(kj >> 32));
            }
        }
    } else {
        // ---- exact per-wave fallback (never taken on this input) ----
        unsigned long long last = 0ull;
        for (int r = 0; r < K; ++r) {
            unsigned long long best = ~0ull;
            for (int i = 0; i < 32; ++i) {
                int v4 = lane + i * 64;
                f4 v = __builtin_nontemporal_load(&row4[v4]);
                int bidx = v4 * 4;
                #pragma unroll
                for (int c = 0; c < 4; ++c) {
                    float d = v[c];
                    float md = (d <= MAX_RADIUS) ? d
                                                 : __uint_as_float(0x7F800000u);
                    unsigned long long key =
                        ((unsigned long long)__float_as_uint(md) << 32) |
                        (unsigned int)(bidx + c);
                    if (((r == 0) || (key > last)) && key < best) best = key;
                }
            }
            #pragma unroll
            for (int off = 32; off > 0; off >>= 1) {
                unsigned long long other = __shfl_xor(best, off, 64);
                if (other < best) best = other;
            }
            if (lane == 0) {
                int idx = (int)(best & 0xFFFFFFFFull);
                s_selidx[wave][r] = idx;
                s_seldist[wave][r] = rowp[idx];  // original dm value
            }
            last = best;
        }
    }

    // ---- outputs (non-temporal: never re-read) ----
    float* out_ei = out;
    float* out_ef = out + (size_t)N_ATOMS * K * 2;
    if (lane < 2 * K) {
        int r = lane >> 1, comp = lane & 1;
        __builtin_nontemporal_store(
            comp ? (float)s_selidx[wave][r] : (float)row,
            &out_ei[((size_t)row * K + r) * 2 + comp]);
    }
    for (int t = lane; t < K * NBINS; t += 64) {
        int r = t / NBINS, b = t - r * NBINS;
        float d = s_seldist[wave][r];
        float z = (d - (float)b * (1.0f / 49.0f)) * 5.0f;
        __builtin_nontemporal_store(__expf(-0.5f * z * z),
                                    &out_ef[(size_t)row * K * NBINS + t]);
    }
}

extern "C" void kernel_launch(void* const* d_in, const int* in_sizes, int n_in,
                              void* d_out, int out_size, void* d_ws, size_t ws_size,
                              hipStream_t stream) {
    const float* dm = (const float*)d_in[0];
    float* out = (float*)d_out;
    edge_kernel<<<N_ATOMS / WAVES, BLOCK, 0, stream>>>(dm, out);
}